// Round 1
// baseline (155.436 us; speedup 1.0000x reference)
//
#include <hip/hip_runtime.h>
#include <hip/hip_bf16.h>

typedef __hip_bfloat16 bf16;
typedef float f32x4 __attribute__((ext_vector_type(4)));
typedef short bf16x8 __attribute__((ext_vector_type(8)));   // 8 bf16 in 4 VGPRs
typedef int   int4v  __attribute__((ext_vector_type(4)));

constexpr int Bb = 2, Ss = 2048, Dd = 1024, Hh = 16, Ww = 128, HDd = 64;
constexpr int Mrows = Bb * Ss;   // 4096

// ---------------------------------------------------------------- conversions
__global__ __launch_bounds__(256) void convert_bf16_k(const float* __restrict__ in,
                                                      bf16* __restrict__ out) {
  size_t i = (size_t)blockIdx.x * 256 + threadIdx.x;   // each thread: 4 elems
  float4 v = reinterpret_cast<const float4*>(in)[i];
  union { bf16 b[4]; ushort4 u; } cv;
  cv.b[0] = __float2bfloat16(v.x);
  cv.b[1] = __float2bfloat16(v.y);
  cv.b[2] = __float2bfloat16(v.z);
  cv.b[3] = __float2bfloat16(v.w);
  reinterpret_cast<ushort4*>(out)[i] = cv.u;
}

// W is [K=1024][N=1024] fp32 row-major; emit Wt = [N][K] bf16 (B^T form)
__global__ __launch_bounds__(256) void transpose_w_k(const float* __restrict__ Win,
                                                     bf16* __restrict__ out) {
  __shared__ float tile[32][33];
  int bx = blockIdx.x, by = blockIdx.y;
  int tx = threadIdx.x & 31, ty = threadIdx.x >> 5;   // 8 rows per pass
#pragma unroll
  for (int i = 0; i < 4; ++i) {
    int k = by * 32 + ty + i * 8;
    int n = bx * 32 + tx;
    tile[ty + i * 8][tx] = Win[(size_t)k * Dd + n];
  }
  __syncthreads();
#pragma unroll
  for (int i = 0; i < 4; ++i) {
    int n = bx * 32 + ty + i * 8;
    int k = by * 32 + tx;
    out[(size_t)n * Dd + k] = __float2bfloat16(tile[tx][ty + i * 8]);
  }
}

// ---------------------------------------------------------------- GEMM (A @ Bt^T)
// A: [M][K] bf16 row-major.  Bt: [N][K] bf16 row-major (i.e. B transposed).
// MODE 0: out bf16 head-split [b][h][s][hd], +bias
// MODE 1: out fp32 [row][col] = acc + bias + resid[row][col]
template <int MODE>
__global__ __launch_bounds__(256) void gemm_bt(const bf16* __restrict__ A,
                                               const bf16* __restrict__ Bt,
                                               const float* __restrict__ bias,
                                               const float* __restrict__ resid,
                                               void* __restrict__ outp) {
  constexpr int BK = 32;
  __shared__ bf16 As[128][BK + 8];
  __shared__ bf16 Bs[128][BK + 8];
  const int t = threadIdx.x;
  const int lane = t & 63, w = t >> 6;
  const int wr = w >> 1, wc = w & 1;
  const int bm = blockIdx.y, bn = blockIdx.x;
  const int l15 = lane & 15, l16 = lane >> 4;

  f32x4 acc[4][4] = {};

  for (int kt = 0; kt < Dd / BK; ++kt) {
    __syncthreads();
#pragma unroll
    for (int i = 0; i < 2; ++i) {
      int chunk = t + 256 * i;            // 0..511
      int row = chunk >> 2;               // 0..127
      int c8 = (chunk & 3) * 8;
      int4v va = *reinterpret_cast<const int4v*>(A + (size_t)(bm * 128 + row) * Dd + kt * BK + c8);
      *reinterpret_cast<int4v*>(&As[row][c8]) = va;
      int4v vb = *reinterpret_cast<const int4v*>(Bt + (size_t)(bn * 128 + row) * Dd + kt * BK + c8);
      *reinterpret_cast<int4v*>(&Bs[row][c8]) = vb;
    }
    __syncthreads();
    bf16x8 af[4], bf[4];
#pragma unroll
    for (int m = 0; m < 4; ++m)
      af[m] = *reinterpret_cast<const bf16x8*>(&As[wr * 64 + m * 16 + l15][l16 * 8]);
#pragma unroll
    for (int n = 0; n < 4; ++n)
      bf[n] = *reinterpret_cast<const bf16x8*>(&Bs[wc * 64 + n * 16 + l15][l16 * 8]);
#pragma unroll
    for (int m = 0; m < 4; ++m)
#pragma unroll
      for (int n = 0; n < 4; ++n)
        acc[m][n] = __builtin_amdgcn_mfma_f32_16x16x32_bf16(af[m], bf[n], acc[m][n], 0, 0, 0);
  }

#pragma unroll
  for (int m = 0; m < 4; ++m) {
    int row_l = wr * 64 + m * 16 + l16 * 4;
#pragma unroll
    for (int n = 0; n < 4; ++n) {
      int col = bn * 128 + wc * 64 + n * 16 + l15;
      float bi = bias[col];
#pragma unroll
      for (int r = 0; r < 4; ++r) {
        int row = bm * 128 + row_l + r;
        float v = acc[m][n][r] + bi;
        if constexpr (MODE == 0) {
          int b = row >> 11, s = row & (Ss - 1);
          int h = col >> 6, hd = col & (HDd - 1);
          bf16* o = (bf16*)outp;
          o[(((size_t)(b * Hh + h)) * Ss + s) * HDd + hd] = __float2bfloat16(v);
        } else {
          float* o = (float*)outp;
          size_t idx = (size_t)row * Dd + col;
          o[idx] = v + resid[idx];
        }
      }
    }
  }
}

// ---------------------------------------------------------------- local attention
// Q,K,V: bf16 [b][h][s][hd].  AO: bf16 [b][s][h*64+hd].
__global__ __launch_bounds__(256) void attn_local(const bf16* __restrict__ Q,
                                                  const bf16* __restrict__ K,
                                                  const bf16* __restrict__ V,
                                                  bf16* __restrict__ AO) {
  constexpr int NKT = 12;                 // 12 key tiles of 16 → span 192
  __shared__ bf16 Vs[64][200];            // V transposed: [hd][klocal]
  __shared__ bf16 Ps[4][16][200];         // per-wave P tile
  const int t = threadIdx.x, lane = t & 63, w = t >> 6;
  const int qb = blockIdx.x, h = blockIdx.y, b = blockIdx.z;
  const int q0 = qb * 64;
  const int kstart = q0 - 128;
  const int l15 = lane & 15, l16 = lane >> 4;
  const bf16* Qh = Q + ((size_t)(b * Hh + h)) * Ss * HDd;
  const bf16* Kh = K + ((size_t)(b * Hh + h)) * Ss * HDd;
  const bf16* Vh = V + ((size_t)(b * Hh + h)) * Ss * HDd;

  // stage V transposed into LDS (zeros for out-of-range keys)
#pragma unroll
  for (int i = 0; i < 6; ++i) {
    int chunk = t + 256 * i;              // 0..1535
    int kl = chunk >> 3;                  // 0..191
    int hc = (chunk & 7) * 8;             // hd chunk base
    int kg = kstart + kl;
    bf16 tmp[8];
    if (kg >= 0) {
      *reinterpret_cast<int4v*>(tmp) = *reinterpret_cast<const int4v*>(Vh + (size_t)kg * HDd + hc);
    } else {
#pragma unroll
      for (int j = 0; j < 8; ++j) tmp[j] = __float2bfloat16(0.f);
    }
#pragma unroll
    for (int j = 0; j < 8; ++j) Vs[hc + j][kl] = tmp[j];
  }

  // Q fragments (wave's 16 query rows, K-dim = hd)
  const int qrow = q0 + w * 16 + l15;
  bf16x8 aq[2];
#pragma unroll
  for (int c = 0; c < 2; ++c)
    aq[c] = *reinterpret_cast<const bf16x8*>(Qh + (size_t)qrow * HDd + c * 32 + l16 * 8);

  // QK^T
  f32x4 sc[NKT];
#pragma unroll
  for (int kt = 0; kt < NKT; ++kt) {
    int key = kstart + kt * 16 + l15;
    bf16x8 bk0 = {0,0,0,0,0,0,0,0}, bk1 = {0,0,0,0,0,0,0,0};
    if (key >= 0) {
      bk0 = *reinterpret_cast<const bf16x8*>(Kh + (size_t)key * HDd + 0  + l16 * 8);
      bk1 = *reinterpret_cast<const bf16x8*>(Kh + (size_t)key * HDd + 32 + l16 * 8);
    }
    f32x4 s = {};
    s = __builtin_amdgcn_mfma_f32_16x16x32_bf16(aq[0], bk0, s, 0, 0, 0);
    s = __builtin_amdgcn_mfma_f32_16x16x32_bf16(aq[1], bk1, s, 0, 0, 0);
    sc[kt] = s;
  }

  // mask + scale + softmax (D-layout: row=(l>>4)*4+r, col=l&15)
  const float scale = 0.125f;
  float mrow[4], ssum[4], inv[4];
  int qg[4];
#pragma unroll
  for (int r = 0; r < 4; ++r) { mrow[r] = -1e30f; qg[r] = q0 + w * 16 + l16 * 4 + r; }
#pragma unroll
  for (int kt = 0; kt < NKT; ++kt) {
    int kg = kstart + kt * 16 + l15;
#pragma unroll
    for (int r = 0; r < 4; ++r) {
      bool valid = (kg >= 0) && (kg <= qg[r]) && (qg[r] - kg < Ww);
      float v = valid ? sc[kt][r] * scale : -1e9f;
      sc[kt][r] = v;
      mrow[r] = fmaxf(mrow[r], v);
    }
  }
#pragma unroll
  for (int r = 0; r < 4; ++r)
#pragma unroll
    for (int off = 1; off < 16; off <<= 1)
      mrow[r] = fmaxf(mrow[r], __shfl_xor(mrow[r], off));
#pragma unroll
  for (int r = 0; r < 4; ++r) ssum[r] = 0.f;
#pragma unroll
  for (int kt = 0; kt < NKT; ++kt)
#pragma unroll
    for (int r = 0; r < 4; ++r) {
      float p = __expf(sc[kt][r] - mrow[r]);
      sc[kt][r] = p;
      ssum[r] += p;
    }
#pragma unroll
  for (int r = 0; r < 4; ++r)
#pragma unroll
    for (int off = 1; off < 16; off <<= 1)
      ssum[r] += __shfl_xor(ssum[r], off);
#pragma unroll
  for (int r = 0; r < 4; ++r) inv[r] = 1.f / ssum[r];

  // unnormalized P → LDS (normalize via inv[] in the epilogue instead)
#pragma unroll
  for (int kt = 0; kt < NKT; ++kt)
#pragma unroll
    for (int r = 0; r < 4; ++r)
      Ps[w][l16 * 4 + r][kt * 16 + l15] = __float2bfloat16(sc[kt][r]);

  __syncthreads();   // covers Vs staging + cross-lane P visibility

  // P @ V
  f32x4 o[4] = {};
#pragma unroll
  for (int kt2 = 0; kt2 < 6; ++kt2) {
    bf16x8 pf = *reinterpret_cast<const bf16x8*>(&Ps[w][l15][kt2 * 32 + l16 * 8]);
#pragma unroll
    for (int ht = 0; ht < 4; ++ht) {
      bf16x8 vf = *reinterpret_cast<const bf16x8*>(&Vs[ht * 16 + l15][kt2 * 32 + l16 * 8]);
      o[ht] = __builtin_amdgcn_mfma_f32_16x16x32_bf16(pf, vf, o[ht], 0, 0, 0);
    }
  }

  // scale by 1/rowsum and write merged-head layout
#pragma unroll
  for (int ht = 0; ht < 4; ++ht)
#pragma unroll
    for (int r = 0; r < 4; ++r) {
      int qw = q0 + w * 16 + l16 * 4 + r;
      int col = h * HDd + ht * 16 + l15;
      AO[(size_t)(b * Ss + qw) * Dd + col] = __float2bfloat16(o[ht][r] * inv[r]);
    }
}

// ---------------------------------------------------------------- LayerNorm (in-place on fp32 y)
__global__ __launch_bounds__(256) void ln_inplace(float* __restrict__ y,
                                                  const float* __restrict__ gamma,
                                                  const float* __restrict__ beta) {
  int row = blockIdx.x;
  float* yr = y + (size_t)row * Dd;
  float4 v = reinterpret_cast<const float4*>(yr)[threadIdx.x];
  float s = v.x + v.y + v.z + v.w;
  float s2 = v.x * v.x + v.y * v.y + v.z * v.z + v.w * v.w;
#pragma unroll
  for (int off = 1; off < 64; off <<= 1) {
    s += __shfl_xor(s, off);
    s2 += __shfl_xor(s2, off);
  }
  __shared__ float r1[4], r2[4];
  int w = threadIdx.x >> 6;
  if ((threadIdx.x & 63) == 0) { r1[w] = s; r2[w] = s2; }
  __syncthreads();
  s = r1[0] + r1[1] + r1[2] + r1[3];
  s2 = r2[0] + r2[1] + r2[2] + r2[3];
  float mu = s * (1.f / Dd);
  float var = s2 * (1.f / Dd) - mu * mu;
  float rs = rsqrtf(var + 1e-5f);
  float4 g = reinterpret_cast<const float4*>(gamma)[threadIdx.x];
  float4 be = reinterpret_cast<const float4*>(beta)[threadIdx.x];
  float4 o;
  o.x = (v.x - mu) * rs * g.x + be.x;
  o.y = (v.y - mu) * rs * g.y + be.y;
  o.z = (v.z - mu) * rs * g.z + be.z;
  o.w = (v.w - mu) * rs * g.w + be.w;
  reinterpret_cast<float4*>(yr)[threadIdx.x] = o;
}

// ---------------------------------------------------------------- launch
extern "C" void kernel_launch(void* const* d_in, const int* in_sizes, int n_in,
                              void* d_out, int out_size, void* d_ws, size_t ws_size,
                              hipStream_t stream) {
  const float* x     = (const float*)d_in[0];
  const float* Wq    = (const float*)d_in[1];
  const float* bq    = (const float*)d_in[2];
  const float* Wk    = (const float*)d_in[3];
  const float* bk    = (const float*)d_in[4];
  const float* Wv    = (const float*)d_in[5];
  const float* bv    = (const float*)d_in[6];
  const float* Wo    = (const float*)d_in[7];
  const float* bo    = (const float*)d_in[8];
  const float* gamma = (const float*)d_in[9];
  const float* beta  = (const float*)d_in[10];
  float* out = (float*)d_out;

  char* ws = (char*)d_ws;
  bf16* xb  = (bf16*)(ws + (size_t)0);          // 8 MB  (4096x1024)
  bf16* WtQ = (bf16*)(ws + ((size_t)8  << 20)); // 2 MB each
  bf16* WtK = (bf16*)(ws + ((size_t)10 << 20));
  bf16* WtV = (bf16*)(ws + ((size_t)12 << 20));
  bf16* WtO = (bf16*)(ws + ((size_t)14 << 20));
  bf16* Qh  = (bf16*)(ws + ((size_t)16 << 20)); // 8 MB each, [b][h][s][hd]
  bf16* Kh  = (bf16*)(ws + ((size_t)24 << 20));
  bf16* Vh  = (bf16*)(ws + ((size_t)32 << 20));
  bf16* AO  = (bf16*)(ws + ((size_t)40 << 20)); // 8 MB, [b][s][d]
  // total 48 MB of d_ws

  convert_bf16_k<<<Mrows * Dd / (256 * 4), 256, 0, stream>>>(x, xb);
  transpose_w_k<<<dim3(32, 32), 256, 0, stream>>>(Wq, WtQ);
  transpose_w_k<<<dim3(32, 32), 256, 0, stream>>>(Wk, WtK);
  transpose_w_k<<<dim3(32, 32), 256, 0, stream>>>(Wv, WtV);
  transpose_w_k<<<dim3(32, 32), 256, 0, stream>>>(Wo, WtO);

  gemm_bt<0><<<dim3(8, 32), 256, 0, stream>>>(xb, WtQ, bq, nullptr, (void*)Qh);
  gemm_bt<0><<<dim3(8, 32), 256, 0, stream>>>(xb, WtK, bk, nullptr, (void*)Kh);
  gemm_bt<0><<<dim3(8, 32), 256, 0, stream>>>(xb, WtV, bv, nullptr, (void*)Vh);

  attn_local<<<dim3(Ss / 64, Hh, Bb), 256, 0, stream>>>(Qh, Kh, Vh, AO);

  gemm_bt<1><<<dim3(8, 32), 256, 0, stream>>>(AO, WtO, bo, x, (void*)out);
  ln_inplace<<<Mrows, 256, 0, stream>>>(out, gamma, beta);
}

// Round 2
// 104.717 us; speedup vs baseline: 1.4843x; 1.4843x over previous
//
#include <hip/hip_runtime.h>
#include <hip/hip_bf16.h>

typedef __hip_bfloat16 bf16;
typedef float f32x4 __attribute__((ext_vector_type(4)));
typedef short bf16x8 __attribute__((ext_vector_type(8)));   // 8 bf16 in 4 VGPRs
typedef int   int4v  __attribute__((ext_vector_type(4)));

constexpr int Bb = 2, Ss = 2048, Dd = 1024, Hh = 16, Ww = 128, HDd = 64;
constexpr int Mrows = Bb * Ss;   // 4096

// async global->LDS, 16B per lane; LDS dest = wave-uniform base + lane*16
__device__ __forceinline__ void gload16(const void* g, void* l) {
  __builtin_amdgcn_global_load_lds(
      (const __attribute__((address_space(1))) void*)g,
      (__attribute__((address_space(3))) void*)l, 16, 0, 0);
}

// ---------------------------------------------------------------- conversions
__global__ __launch_bounds__(256) void convert_bf16_k(const float* __restrict__ in,
                                                      bf16* __restrict__ out) {
  size_t i = (size_t)blockIdx.x * 256 + threadIdx.x;   // each thread: 4 elems
  float4 v = reinterpret_cast<const float4*>(in)[i];
  union { bf16 b[4]; ushort4 u; } cv;
  cv.b[0] = __float2bfloat16(v.x);
  cv.b[1] = __float2bfloat16(v.y);
  cv.b[2] = __float2bfloat16(v.z);
  cv.b[3] = __float2bfloat16(v.w);
  reinterpret_cast<ushort4*>(out)[i] = cv.u;
}

// 4 weights [K][N] fp32 -> contiguous bf16 [4][N][K] (B^T form), z picks weight
__global__ __launch_bounds__(256) void transpose_w4_k(const float* __restrict__ W0,
                                                      const float* __restrict__ W1,
                                                      const float* __restrict__ W2,
                                                      const float* __restrict__ W3,
                                                      bf16* __restrict__ out) {
  const float* Win = (blockIdx.z == 0) ? W0 : (blockIdx.z == 1) ? W1
                     : (blockIdx.z == 2) ? W2 : W3;
  bf16* o = out + (size_t)blockIdx.z * Dd * Dd;
  __shared__ float tile[32][33];
  int bx = blockIdx.x, by = blockIdx.y;
  int tx = threadIdx.x & 31, ty = threadIdx.x >> 5;
#pragma unroll
  for (int i = 0; i < 4; ++i) {
    int k = by * 32 + ty + i * 8;
    int n = bx * 32 + tx;
    tile[ty + i * 8][tx] = Win[(size_t)k * Dd + n];
  }
  __syncthreads();
#pragma unroll
  for (int i = 0; i < 4; ++i) {
    int n = bx * 32 + ty + i * 8;
    int k = by * 32 + tx;
    o[(size_t)n * Dd + k] = __float2bfloat16(tile[tx][ty + i * 8]);
  }
}

// ---------------------------------------------------------------- GEMM core (m97 structure)
// A: [M][K] bf16, Bt: [N][K] bf16. 128x128 tile, BK=32, linear LDS + global_load_lds.
__device__ __forceinline__ void gemm_core(const bf16* __restrict__ A,
                                          const bf16* __restrict__ Bt,
                                          int bm, int bn,
                                          bf16* As, bf16* Bs, f32x4 acc[4][4]) {
  const int t = threadIdx.x;
  const int lane = t & 63, w = t >> 6;
  const int wr = w >> 1, wc = w & 1;
  const int l15 = lane & 15, l16 = lane >> 4;
  const bf16* Arow0 = A + (size_t)bm * 128 * Dd;
  const bf16* Brow0 = Bt + (size_t)bn * 128 * Dd;

  for (int kt = 0; kt < Dd / 32; ++kt) {
    __syncthreads();                       // prev iteration's ds_reads done
#pragma unroll
    for (int i = 0; i < 2; ++i) {
      int chunk = i * 256 + t;             // 0..511: row=chunk>>2, 8-col=chunk&3
      int row = chunk >> 2, c8 = (chunk & 3) * 8;
      gload16(Arow0 + (size_t)row * Dd + kt * 32 + c8, As + chunk * 8);
      gload16(Brow0 + (size_t)row * Dd + kt * 32 + c8, Bs + chunk * 8);
    }
    __syncthreads();                       // drains vmcnt, data visible
    bf16x8 af[4], bfr[4];
#pragma unroll
    for (int m = 0; m < 4; ++m)
      af[m] = *reinterpret_cast<const bf16x8*>(As + (wr * 64 + m * 16 + l15) * 32 + l16 * 8);
#pragma unroll
    for (int n = 0; n < 4; ++n)
      bfr[n] = *reinterpret_cast<const bf16x8*>(Bs + (wc * 64 + n * 16 + l15) * 32 + l16 * 8);
#pragma unroll
    for (int m = 0; m < 4; ++m)
#pragma unroll
      for (int n = 0; n < 4; ++n)
        acc[m][n] = __builtin_amdgcn_mfma_f32_16x16x32_bf16(af[m], bfr[n], acc[m][n], 0, 0, 0);
  }
}

// Fused QKV projection: Wt3 = [3072][1024]. Q,K head-split [b][h][s][hd]; V transposed [b][h][hd][s].
__global__ __launch_bounds__(256) void gemm_qkv(const bf16* __restrict__ A,
                                                const bf16* __restrict__ Wt3,
                                                const float* __restrict__ bq,
                                                const float* __restrict__ bk,
                                                const float* __restrict__ bv,
                                                bf16* __restrict__ Qh,
                                                bf16* __restrict__ Kh,
                                                bf16* __restrict__ Vt) {
  __shared__ bf16 As[128 * 32], Bs[128 * 32];
  f32x4 acc[4][4] = {};
  const int bm = blockIdx.y, bn = blockIdx.x;
  gemm_core(A, Wt3, bm, bn, As, Bs, acc);

  const int lane = threadIdx.x & 63, w = threadIdx.x >> 6;
  const int wr = w >> 1, wc = w & 1, l15 = lane & 15, l16 = lane >> 4;
#pragma unroll
  for (int n = 0; n < 4; ++n) {
    int colg = bn * 128 + wc * 64 + n * 16 + l15;   // 0..3071
    int p = colg >> 10, c = colg & 1023;
    int h = c >> 6, hd = c & (HDd - 1);
    const float* bp = (p == 0) ? bq : (p == 1) ? bk : bv;
    float bi = bp[c];
#pragma unroll
    for (int m = 0; m < 4; ++m) {
      int s0 = bm * 128 + wr * 64 + m * 16 + l16 * 4;   // global row of first r
      int b = s0 >> 11, s = s0 & (Ss - 1);
      if (p < 2) {
        bf16* o = p ? Kh : Qh;
        size_t base = (((size_t)(b * Hh + h)) * Ss + s) * HDd + hd;
#pragma unroll
        for (int r = 0; r < 4; ++r)
          o[base + (size_t)r * HDd] = __float2bfloat16(acc[m][n][r] + bi);
      } else {
        union { ushort4 u; ushort e[4]; } pk;
#pragma unroll
        for (int r = 0; r < 4; ++r) {
          bf16 tb = __float2bfloat16(acc[m][n][r] + bi);
          pk.e[r] = *reinterpret_cast<ushort*>(&tb);
        }
        *reinterpret_cast<ushort4*>(&Vt[(((size_t)(b * Hh + h)) * HDd + hd) * Ss + s]) = pk.u;
      }
    }
  }
}

// O projection + bias + residual, fp32 out
__global__ __launch_bounds__(256) void gemm_o(const bf16* __restrict__ A,
                                              const bf16* __restrict__ Wt,
                                              const float* __restrict__ bias,
                                              const float* __restrict__ resid,
                                              float* __restrict__ out) {
  __shared__ bf16 As[128 * 32], Bs[128 * 32];
  f32x4 acc[4][4] = {};
  const int bm = blockIdx.y, bn = blockIdx.x;
  gemm_core(A, Wt, bm, bn, As, Bs, acc);

  const int lane = threadIdx.x & 63, w = threadIdx.x >> 6;
  const int wr = w >> 1, wc = w & 1, l15 = lane & 15, l16 = lane >> 4;
#pragma unroll
  for (int m = 0; m < 4; ++m) {
    int row_l = wr * 64 + m * 16 + l16 * 4;
#pragma unroll
    for (int n = 0; n < 4; ++n) {
      int col = bn * 128 + wc * 64 + n * 16 + l15;
      float bi = bias[col];
#pragma unroll
      for (int r = 0; r < 4; ++r) {
        int row = bm * 128 + row_l + r;
        size_t idx = (size_t)row * Dd + col;
        out[idx] = acc[m][n][r] + bi + resid[idx];
      }
    }
  }
}

// ---------------------------------------------------------------- local attention
// Q,K: bf16 [b][h][s][hd]. Vt: bf16 [b][h][hd][s]. AO: bf16 [b][s][h*64+hd].
// Block = 64 queries x one (b,h); 4 waves x 16 q-rows. No V staging (L2-resident).
__global__ __launch_bounds__(256) void attn_local(const bf16* __restrict__ Q,
                                                  const bf16* __restrict__ K,
                                                  const bf16* __restrict__ Vt,
                                                  bf16* __restrict__ AO) {
  __shared__ bf16 Ps[4][16][200];          // per-wave P[q][key], 25.6 KB
  const int t = threadIdx.x, lane = t & 63, w = t >> 6;
  const int l15 = lane & 15, l16 = lane >> 4;
  const int qb = blockIdx.x, h = blockIdx.y, b = blockIdx.z;
  const int q0 = qb * 64, kstart = q0 - 128;
  const bf16* Qp = Q + ((size_t)(b * Hh + h)) * Ss * HDd;
  const bf16* Kp = K + ((size_t)(b * Hh + h)) * Ss * HDd;
  const bf16* Vp = Vt + ((size_t)(b * Hh + h)) * HDd * Ss;

  // Q fragments (A-operand rows = l15)
  const int qrow = q0 + w * 16 + l15;
  bf16x8 aq0 = *reinterpret_cast<const bf16x8*>(Qp + (size_t)qrow * HDd + l16 * 8);
  bf16x8 aq1 = *reinterpret_cast<const bf16x8*>(Qp + (size_t)qrow * HDd + 32 + l16 * 8);

  // QK^T: wave w only needs key tiles kt = w .. w+8 (rest fully masked)
  f32x4 sc[9];
#pragma unroll
  for (int j = 0; j < 9; ++j) {
    int key = kstart + (w + j) * 16 + l15;
    int kc = key < 0 ? 0 : key;            // clamp; masked later
    bf16x8 bk0 = *reinterpret_cast<const bf16x8*>(Kp + (size_t)kc * HDd + l16 * 8);
    bf16x8 bk1 = *reinterpret_cast<const bf16x8*>(Kp + (size_t)kc * HDd + 32 + l16 * 8);
    f32x4 s = {};
    s = __builtin_amdgcn_mfma_f32_16x16x32_bf16(aq0, bk0, s, 0, 0, 0);
    s = __builtin_amdgcn_mfma_f32_16x16x32_bf16(aq1, bk1, s, 0, 0, 0);
    sc[j] = s;
  }

  // mask + scale + softmax (D-layout: row=(l>>4)*4+r, col=l&15)
  const float scale = 0.125f;
  float mrow[4], ssum[4], inv[4];
  int qg[4];
#pragma unroll
  for (int r = 0; r < 4; ++r) { mrow[r] = -1e30f; qg[r] = q0 + w * 16 + l16 * 4 + r; }
#pragma unroll
  for (int j = 0; j < 9; ++j) {
    int kg = kstart + (w + j) * 16 + l15;
#pragma unroll
    for (int r = 0; r < 4; ++r) {
      bool valid = (kg >= 0) && (kg <= qg[r]) && (qg[r] - kg < Ww);
      float v = valid ? sc[j][r] * scale : -1e9f;
      sc[j][r] = v;
      mrow[r] = fmaxf(mrow[r], v);
    }
  }
#pragma unroll
  for (int r = 0; r < 4; ++r)
#pragma unroll
    for (int off = 1; off < 16; off <<= 1)
      mrow[r] = fmaxf(mrow[r], __shfl_xor(mrow[r], off));
#pragma unroll
  for (int r = 0; r < 4; ++r) ssum[r] = 0.f;
#pragma unroll
  for (int j = 0; j < 9; ++j)
#pragma unroll
    for (int r = 0; r < 4; ++r) {
      float p = __expf(sc[j][r] - mrow[r]);
      sc[j][r] = p;
      ssum[r] += p;
    }
#pragma unroll
  for (int r = 0; r < 4; ++r)
#pragma unroll
    for (int off = 1; off < 16; off <<= 1)
      ssum[r] += __shfl_xor(ssum[r], off);
#pragma unroll
  for (int r = 0; r < 4; ++r) inv[r] = 1.f / ssum[r];

  // unnormalized P -> LDS (9 computed tiles + 1 zero tile covering PV read range)
#pragma unroll
  for (int j = 0; j < 9; ++j)
#pragma unroll
    for (int r = 0; r < 4; ++r)
      Ps[w][l16 * 4 + r][(w + j) * 16 + l15] = __float2bfloat16(sc[j][r]);
  {
    int ktz = (w & 1) ? (w - 1) : (w + 9);
    bf16 z16 = __float2bfloat16(0.f);
#pragma unroll
    for (int r = 0; r < 4; ++r)
      Ps[w][l16 * 4 + r][ktz * 16 + l15] = z16;
  }
  // per-wave LDS: same wave writes then reads -> compiler lgkmcnt handles it

  // P @ V  (V^T fragments straight from global; 32-key chunks c0..c0+4)
  const int c0 = w >> 1;
  f32x4 o[4] = {};
#pragma unroll
  for (int cc = 0; cc < 5; ++cc) {
    int c = c0 + cc;
    bf16x8 pf = *reinterpret_cast<const bf16x8*>(&Ps[w][l15][c * 32 + l16 * 8]);
    int kk = kstart + c * 32 + l16 * 8;
    int kc = kk < 0 ? 0 : kk;              // whole 8-chunk invalid => P==0 anyway
#pragma unroll
    for (int ht = 0; ht < 4; ++ht) {
      bf16x8 vf = *reinterpret_cast<const bf16x8*>(Vp + (size_t)(ht * 16 + l15) * Ss + kc);
      o[ht] = __builtin_amdgcn_mfma_f32_16x16x32_bf16(pf, vf, o[ht], 0, 0, 0);
    }
  }

  // normalize and write merged-head layout
#pragma unroll
  for (int ht = 0; ht < 4; ++ht)
#pragma unroll
    for (int r = 0; r < 4; ++r) {
      int qw = q0 + w * 16 + l16 * 4 + r;
      int col = h * HDd + ht * 16 + l15;
      AO[(size_t)(b * Ss + qw) * Dd + col] = __float2bfloat16(o[ht][r] * inv[r]);
    }
}

// ---------------------------------------------------------------- LayerNorm (in-place on fp32 y)
__global__ __launch_bounds__(256) void ln_inplace(float* __restrict__ y,
                                                  const float* __restrict__ gamma,
                                                  const float* __restrict__ beta) {
  int row = blockIdx.x;
  float* yr = y + (size_t)row * Dd;
  float4 v = reinterpret_cast<const float4*>(yr)[threadIdx.x];
  float s = v.x + v.y + v.z + v.w;
  float s2 = v.x * v.x + v.y * v.y + v.z * v.z + v.w * v.w;
#pragma unroll
  for (int off = 1; off < 64; off <<= 1) {
    s += __shfl_xor(s, off);
    s2 += __shfl_xor(s2, off);
  }
  __shared__ float r1[4], r2[4];
  int w = threadIdx.x >> 6;
  if ((threadIdx.x & 63) == 0) { r1[w] = s; r2[w] = s2; }
  __syncthreads();
  s = r1[0] + r1[1] + r1[2] + r1[3];
  s2 = r2[0] + r2[1] + r2[2] + r2[3];
  float mu = s * (1.f / Dd);
  float var = s2 * (1.f / Dd) - mu * mu;
  float rs = rsqrtf(var + 1e-5f);
  float4 g = reinterpret_cast<const float4*>(gamma)[threadIdx.x];
  float4 be = reinterpret_cast<const float4*>(beta)[threadIdx.x];
  float4 o;
  o.x = (v.x - mu) * rs * g.x + be.x;
  o.y = (v.y - mu) * rs * g.y + be.y;
  o.z = (v.z - mu) * rs * g.z + be.z;
  o.w = (v.w - mu) * rs * g.w + be.w;
  reinterpret_cast<float4*>(yr)[threadIdx.x] = o;
}

// ---------------------------------------------------------------- launch
extern "C" void kernel_launch(void* const* d_in, const int* in_sizes, int n_in,
                              void* d_out, int out_size, void* d_ws, size_t ws_size,
                              hipStream_t stream) {
  const float* x     = (const float*)d_in[0];
  const float* Wq    = (const float*)d_in[1];
  const float* bq    = (const float*)d_in[2];
  const float* Wk    = (const float*)d_in[3];
  const float* bk    = (const float*)d_in[4];
  const float* Wv    = (const float*)d_in[5];
  const float* bv    = (const float*)d_in[6];
  const float* Wo    = (const float*)d_in[7];
  const float* bo    = (const float*)d_in[8];
  const float* gamma = (const float*)d_in[9];
  const float* beta  = (const float*)d_in[10];
  float* out = (float*)d_out;

  char* ws = (char*)d_ws;
  bf16* xb  = (bf16*)(ws + (size_t)0);          // 8 MB  (4096x1024)
  bf16* WtQ = (bf16*)(ws + ((size_t)8  << 20)); // 2 MB each; Q,K,V contiguous = Wt3
  bf16* WtO = (bf16*)(ws + ((size_t)14 << 20));
  bf16* Qh  = (bf16*)(ws + ((size_t)16 << 20)); // [b][h][s][hd]
  bf16* Kh  = (bf16*)(ws + ((size_t)24 << 20)); // [b][h][s][hd]
  bf16* Vt  = (bf16*)(ws + ((size_t)32 << 20)); // [b][h][hd][s]  (transposed!)
  bf16* AO  = (bf16*)(ws + ((size_t)40 << 20)); // [b][s][d]

  convert_bf16_k<<<Mrows * Dd / (256 * 4), 256, 0, stream>>>(x, xb);
  transpose_w4_k<<<dim3(32, 32, 4), 256, 0, stream>>>(Wq, Wk, Wv, Wo, WtQ);

  gemm_qkv<<<dim3(24, 32), 256, 0, stream>>>(xb, WtQ, bq, bk, bv, Qh, Kh, Vt);

  attn_local<<<dim3(Ss / 64, Hh, Bb), 256, 0, stream>>>(Qh, Kh, Vt, AO);

  gemm_o<<<dim3(8, 32), 256, 0, stream>>>(AO, WtO, bo, x, out);
  ln_inplace<<<Mrows, 256, 0, stream>>>(out, gamma, beta);
}